// Round 16
// baseline (791.078 us; speedup 1.0000x reference)
//
#include <hip/hip_runtime.h>
#include <hip/hip_bf16.h>

// ---------------- problem constants ----------------
#define NN 30000
#define NE 480000
#define CIN 64
#define KD 1600          // 25*64 spline-K dimension
#define KT 1664          // + 64 root-append columns
#define KMAC 13          // K macro-steps of 128
#define BM 64            // GEMM rows per block
#define NBLK 469         // ceil(30000/64)
#define MROWS (NBLK*BM)  // 30016 (A rows incl. pad)
#define NBS 118          // scan blocks: ceil(30000/256)
#define REG_OFF  (30000*101)
#define OBJ_OFF  (30000*105)

typedef short bf16x8 __attribute__((ext_vector_type(8)));
typedef float f32x4  __attribute__((ext_vector_type(4)));
typedef __attribute__((address_space(3))) unsigned lds_u32;
typedef __attribute__((address_space(1))) const unsigned glb_u32;

__device__ __forceinline__ ushort f2bf(float x) {
    union { float f; unsigned u; } v; v.f = x;
    unsigned r = v.u + 0x7FFFu + ((v.u >> 16) & 1u);   // RNE
    return (ushort)(r >> 16);
}
__device__ __forceinline__ float bf2f(ushort u) {
    union { unsigned i; float f; } v; v.i = ((unsigned)u) << 16; return v.f;
}
__device__ __forceinline__ float bflo(unsigned u) {
    union { unsigned i; float f; } v; v.i = u << 16; return v.f;
}
__device__ __forceinline__ float bfhi(unsigned u) {
    union { unsigned i; float f; } v; v.i = u & 0xFFFF0000u; return v.f;
}

#define WAITV2 asm volatile("s_waitcnt vmcnt(2)" ::: "memory")
#define WAITV0 asm volatile("s_waitcnt vmcnt(0)" ::: "memory")

// ---------------- graph preprocessing ----------------
__global__ void k_count(const int* __restrict__ dst, int* __restrict__ deg) {
    int e = blockIdx.x * 256 + threadIdx.x;
    if (e < NE) atomicAdd(&deg[dst[e]], 1);
}

// 3-stage parallel exclusive scan of deg[30000] -> rp/cur/invd
__global__ void k_scan1(const int* __restrict__ deg, int* __restrict__ bsum) {
    __shared__ int sred[4];
    int i = blockIdx.x * 256 + threadIdx.x;
    int v = (i < NN) ? deg[i] : 0;
    #pragma unroll
    for (int o = 32; o >= 1; o >>= 1) v += __shfl_down(v, o);
    int w = threadIdx.x >> 6, l = threadIdx.x & 63;
    if (l == 0) sred[w] = v;
    __syncthreads();
    if (threadIdx.x == 0) bsum[blockIdx.x] = sred[0] + sred[1] + sred[2] + sred[3];
}

__global__ void k_scan2(const int* __restrict__ bsum, int* __restrict__ boff) {
    __shared__ int s[128];
    int t = threadIdx.x;
    int v = (t < NBS) ? bsum[t] : 0;
    s[t] = v; __syncthreads();
    for (int o = 1; o < 128; o <<= 1) {
        int u = (t >= o) ? s[t - o] : 0;
        __syncthreads(); s[t] += u; __syncthreads();
    }
    if (t < NBS) boff[t] = s[t] - v;          // exclusive block offset
}

__global__ void k_scan3(const int* __restrict__ deg, const int* __restrict__ boff,
                        int* __restrict__ rp, int* __restrict__ cur, float* __restrict__ invd) {
    __shared__ int s[256];
    int t = threadIdx.x;
    int i = blockIdx.x * 256 + t;
    int v = (i < NN) ? deg[i] : 0;
    s[t] = v; __syncthreads();
    for (int o = 1; o < 256; o <<= 1) {
        int u = (t >= o) ? s[t - o] : 0;
        __syncthreads(); s[t] += u; __syncthreads();
    }
    int ex = s[t] - v + boff[blockIdx.x];
    if (i < NN) {
        rp[i] = ex; cur[i] = ex;
        invd[i] = 1.f / (float)(v > 0 ? v : 1);
    }
    if (i == NN - 1) rp[NN] = NE;
}

// spline basis per edge, scattered into dst-sorted order as ONE 16-B record:
// { k00 | (src<<8), bf16{B00,B01}, bf16{B10,B11}, 0 } with invd[dst] FOLDED into B.
__global__ void k_scatter(const float* __restrict__ ea, const int* __restrict__ src,
                          const int* __restrict__ dst, int* __restrict__ cur,
                          const float* __restrict__ invd, uint4* __restrict__ mE) {
    int e = blockIdx.x * 256 + threadIdx.x;
    if (e >= NE) return;
    float p0 = ea[e*3+0], p1 = ea[e*3+1];
    float v0 = p0*4.f, v1 = p1*4.f;
    float b0 = fminf(fmaxf(floorf(v0),0.f),4.f);
    float b1 = fminf(fmaxf(floorf(v1),0.f),4.f);
    float f0 = v0-b0, f1 = v1-b1;
    int i0 = (int)b0, i1 = (int)b1;
    int dn = dst[e];
    float s = invd[dn];
    float B00 = (1.f-f0)*(1.f-f1)*s;
    float B01 = (1.f-f0)*f1*s;
    float B10 = f0*(1.f-f1)*s;
    float B11 = f0*f1*s;
    int k00 = i0*5 + i1;
    int pos = atomicAdd(&cur[dn], 1);
    unsigned w01 = (unsigned)f2bf(B00) | ((unsigned)f2bf(B01) << 16);
    unsigned w23 = (unsigned)f2bf(B10) | ((unsigned)f2bf(B11) << 16);
    mE[pos] = make_uint4((unsigned)k00 | ((unsigned)src[e] << 8), w01, w23, 0u);
}

// pack+transpose weights to bf16 [outcol][KT]:
// T1: 64 rows. T23: 128 rows (W2 | W3). Tr: 16 rows (4 valid). TcTo: 128 rows (Wc 112 | Wo 16).
__global__ void k_prepw(const float* W1,const float* R1,const float* W2,const float* R2,
                        const float* W3,const float* R3,const float* Wr,const float* Rr,
                        const float* Wc,const float* Rc,const float* Wo,const float* Ro,
                        ushort* T1, ushort* T23, ushort* Tr, ushort* TcTo) {
    int b = blockIdx.x;
    const float* W; const float* R; ushort* T; int od; int col;
    if      (b < 64)  { W=W1; R=R1; T=T1  + (long)b*KT;       od=64;  col=b;     }
    else if (b < 128) { W=W2; R=R2; T=T23 + (long)(b-64)*KT;  od=64;  col=b-64;  }
    else if (b < 192) { W=W3; R=R3; T=T23 + (long)(b-64)*KT;  od=64;  col=b-128; }
    else if (b < 208) { W=Wr; R=Rr; T=Tr  + (long)(b-192)*KT; od=4;   col=b-192; }
    else if (b < 320) { W=Wc; R=Rc; T=TcTo+ (long)(b-208)*KT; od=101; col=b-208; }
    else              { W=Wo; R=Ro; T=TcTo+ (long)(b-208)*KT; od=1;   col=b-320; }
    for (int kc = threadIdx.x; kc < KT; kc += 256) {
        float v = 0.f;
        if (col < od) v = (kc < KD) ? W[(long)kc*od + col] : R[(long)(kc-KD)*od + col];
        T[kc] = f2bf(v);
    }
}

// ---------------- feature prep: bf16 gather source (L2-resident, 3.84 MB) ----------------
__global__ void k_cvt(const float* __restrict__ x, ushort* __restrict__ xb) {
    int idx = blockIdx.x * 1024 + threadIdx.x;
    if (idx < NN*CIN) xb[idx] = f2bf(x[idx]);
}

// BN+ReLU applied ONCE per element (not per edge): y f32 + stats -> bf16 normalized
__global__ void k_norm(const float* __restrict__ y, const float* __restrict__ st,
                       const float* __restrict__ g, const float* __restrict__ be,
                       ushort* __restrict__ xb) {
    int idx = blockIdx.x * 1024 + threadIdx.x;
    if (idx >= NN*CIN) return;
    int d = idx & 63;
    const float inv_n = 1.f / (float)NN;
    float m = st[d] * inv_n;
    float var = st[64 + d] * inv_n - m * m;
    float a = g[d] * rsqrtf(var + 1e-5f);
    float c = be[d] - m * a;
    xb[idx] = f2bf(fmaxf(y[idx] * a + c, 0.f));
}

// ---------------- aggregation: one wave per node, 8-edge batches, 2-stage pipeline ----------
// Batch i+1's meta-load + gathers are issued BEFORE batch i's consume, so the
// meta(~500cy)->gather(~500cy) chain is exposed ~once per node, not per batch.
#define AGGC(K, A_, B_, C_, D_) case K: A_ += b0v*xu; B_ += b1v*xu; C_ += b2v*xu; D_ += b3v*xu; break;

__global__ void k_agg(
                      const int* __restrict__ rp, const uint4* __restrict__ mE,
                      const ushort* __restrict__ f, ushort* __restrict__ A) {
    int wid = (blockIdx.x * 256 + threadIdx.x) >> 6;
    wid = __builtin_amdgcn_readfirstlane(wid);   // wave-uniform -> scalar loads for rp/mE
    int l = threadIdx.x & 63;
    if (wid >= NN) return;
    float a00=0.f,a01=0.f,a02=0.f,a03=0.f,a04=0.f;
    float a05=0.f,a06=0.f,a07=0.f,a08=0.f,a09=0.f;
    float a10=0.f,a11=0.f,a12=0.f,a13=0.f,a14=0.f;
    float a15=0.f,a16=0.f,a17=0.f,a18=0.f,a19=0.f;
    float a20=0.f,a21=0.f,a22=0.f,a23=0.f,a24=0.f;
    int beg = rp[wid], end = rp[wid + 1];

    auto ldm = [&](int e0, uint4* mm) {
        #pragma unroll
        for (int u = 0; u < 8; ++u) {
            int e = e0 + u;
            mm[u] = mE[(e < end) ? e : beg];
            if (e >= end) { mm[u].y = 0u; mm[u].z = 0u; }
        }
    };
    auto gth = [&](const uint4* mm, ushort* xx) {
        #pragma unroll
        for (int u = 0; u < 8; ++u) xx[u] = f[(long)(mm[u].x >> 8) * CIN + l];
    };
    auto consume = [&](const uint4* mm, const ushort* xx) {
        #pragma unroll
        for (int u = 0; u < 8; ++u) {
            float xu = bf2f(xx[u]);
            float b0v = bflo(mm[u].y), b1v = bfhi(mm[u].y);
            float b2v = bflo(mm[u].z), b3v = bfhi(mm[u].z);
            int k00 = __builtin_amdgcn_readfirstlane(mm[u].x & 0xFFu);
            switch (k00) {
                AGGC(0,  a00,a01,a05,a06)
                AGGC(1,  a01,a02,a06,a07)
                AGGC(2,  a02,a03,a07,a08)
                AGGC(3,  a03,a04,a08,a09)
                AGGC(5,  a05,a06,a10,a11)
                AGGC(6,  a06,a07,a11,a12)
                AGGC(7,  a07,a08,a12,a13)
                AGGC(8,  a08,a09,a13,a14)
                AGGC(10, a10,a11,a15,a16)
                AGGC(11, a11,a12,a16,a17)
                AGGC(12, a12,a13,a17,a18)
                AGGC(13, a13,a14,a18,a19)
                AGGC(15, a15,a16,a20,a21)
                AGGC(16, a16,a17,a21,a22)
                AGGC(17, a17,a18,a22,a23)
                AGGC(18, a18,a19,a23,a24)
                default: break;
            }
        }
    };

    // 2-stage pipeline over 8-edge batches (static A/B buffers, wave-uniform control)
    uint4 mA[8], mB_[8];
    ushort xA[8], xB_[8];
    ldm(beg, mA); gth(mA, xA);
    for (int e0 = beg; e0 < end; e0 += 16) {
        bool hasB = (e0 + 8) < end;
        if (hasB) { ldm(e0 + 8, mB_); gth(mB_, xB_); }
        __builtin_amdgcn_sched_barrier(0);
        consume(mA, xA);
        if (hasB) {
            bool hasC = (e0 + 16) < end;
            if (hasC) { ldm(e0 + 16, mA); gth(mA, xA); }   // prefetch next into A
            __builtin_amdgcn_sched_barrier(0);
            consume(mB_, xB_);
        }
    }

    ushort* rb = A + (long)wid * KT + l;
    #define STO(K, V) rb[K*CIN] = f2bf(V);
    STO(0,a00)  STO(1,a01)  STO(2,a02)  STO(3,a03)  STO(4,a04)
    STO(5,a05)  STO(6,a06)  STO(7,a07)  STO(8,a08)  STO(9,a09)
    STO(10,a10) STO(11,a11) STO(12,a12) STO(13,a13) STO(14,a14)
    STO(15,a15) STO(16,a16) STO(17,a17) STO(18,a18) STO(19,a19)
    STO(20,a20) STO(21,a21) STO(22,a22) STO(23,a23) STO(24,a24)
    #undef STO
    rb[KD] = f[(long)wid * CIN + l];           // root-append: raw bf16 copy
}

// ---------------- GEMM: A[30016 x 1664] bf16 x B[N x 1664] bf16 -> f32 ----------------
// BM=64, BK=128, 512 threads (8 waves), TRIPLE-buffered LDS (3 x 16 KB), depth-2 prefetch.
// Counted vmcnt + raw s_barrier; B-loads issued before stage intrinsics each iteration.
// MODE 0: N=64  (T1)  -> y1 + st1, K-split [0,7)/[7,13)
// MODE 1: N=128 (T23) -> waves 0-3: y2+st2, waves 4-7: y3+st3
// MODE 2: N=16  (Tr)  -> K round-robin over 8 waves + LDS reduce, 4 valid cols, bias
// MODE 3: N=128 (TcTo)-> waves 0-6: cls (101 valid, bias), wave 7: obj (1 col, bias)
template<int MODE>
__global__ void k_gemm(const ushort* __restrict__ A, const ushort* __restrict__ B,
                       float* __restrict__ o0, float* __restrict__ o1,
                       float* __restrict__ s0, float* __restrict__ s1,
                       const float* __restrict__ b0, const float* __restrict__ b1) {
    __shared__ ushort As[3 * 8192];           // 3 x 16 KB
    f32x4* part = (f32x4*)As;                 // epilogue overlay (all loads drained by then)
    const int tid = threadIdx.x, w = tid >> 6, l = tid & 63;
    const int m0 = blockIdx.x * BM;

    int colrow;
    if constexpr (MODE == 0)      colrow = ((w & 3) << 4) + (l & 15);
    else if constexpr (MODE == 2) colrow = (l & 15);
    else                          colrow = (w << 4) + (l & 15);
    const ushort* Bp = B + (long)colrow * KT + ((l >> 4) << 3);

    // staging: wave w covers rows w*8 .. w*8+7
    const int row0 = (w << 3) + (l >> 4);
    const int row1 = row0 + 4;
    const ushort* g0 = A + (long)(m0 + row0) * KT + (((l & 15) ^ (row0 & 7)) << 3);
    const ushort* g1 = A + (long)(m0 + row1) * KT + (((l & 15) ^ (row1 & 7)) << 3);
    ushort* d0 = (ushort*)As + (w << 10);     // wave base (bytes: w*2048)
    ushort* d1 = d0 + 512;                    // + 1024 B

    auto stage = [&](int ks, int bf) {
        const ushort* sA = g0 + ks * 128;
        const ushort* sB = g1 + ks * 128;
        __builtin_amdgcn_global_load_lds((glb_u32*)sA, (lds_u32*)(d0 + bf * 8192), 16, 0, 0);
        __builtin_amdgcn_global_load_lds((glb_u32*)sB, (lds_u32*)(d1 + bf * 8192), 16, 0, 0);
    };

    f32x4 acc[4];
    #pragma unroll
    for (int m = 0; m < 4; ++m) acc[m] = (f32x4){0.f,0.f,0.f,0.f};

    stage(0, 0);
    stage(1, 1);
    WAITV2;                                   // tile 0 done, tile 1 in flight
    __builtin_amdgcn_s_barrier();
    __builtin_amdgcn_sched_barrier(0);

    for (int ks = 0; ks < KMAC; ++ks) {
        const int bufc = ks % 3;
        bool act;
        if constexpr (MODE == 0)      act = (w < 4) ? (ks < 7) : (ks >= 7);
        else if constexpr (MODE == 2) act = ((ks & 7) == w);
        else                          act = true;
        if (act) {
            bf16x8 bb[4];
            #pragma unroll
            for (int s = 0; s < 4; ++s) bb[s] = *(const bf16x8*)(Bp + ks * 128 + s * 32);
            if (ks + 2 < KMAC) stage(ks + 2, (ks + 2) % 3);   // issued AFTER B-loads
            const char* Ab = (const char*)As + bufc * 16384;
            #pragma unroll
            for (int s = 0; s < 4; ++s) {
                #pragma unroll
                for (int m = 0; m < 4; ++m) {
                    int r = (m << 4) + (l & 15);
                    int j = (s << 2) + (l >> 4);
                    bf16x8 a = *(const bf16x8*)(Ab + r * 256 + ((j ^ (r & 7)) << 4));
                    acc[m] = __builtin_amdgcn_mfma_f32_16x16x32_bf16(a, bb[s], acc[m], 0, 0, 0);
                }
            }
        } else {
            if (ks + 2 < KMAC) stage(ks + 2, (ks + 2) % 3);
        }
        if (ks < KMAC - 2) { WAITV2; } else { WAITV0; }
        __builtin_amdgcn_s_barrier();
        __builtin_amdgcn_sched_barrier(0);
    }

    // ---- epilogue (part[] overlays As; all loads drained) ----
    auto emit = [&](f32x4* ac, float* out, int ostride, int col, int odcap, float bv, float* stats) {
        float p1 = 0.f, p2 = 0.f;
        #pragma unroll
        for (int m = 0; m < 4; ++m) {
            #pragma unroll
            for (int r = 0; r < 4; ++r) {
                int row = m0 + (m << 4) + ((l >> 4) << 2) + r;
                if (row < NN) {
                    float v = ac[m][r] + bv;
                    if (col < odcap) out[(long)row * ostride + col] = v;
                    p1 += v; p2 += v * v;
                }
            }
        }
        if (stats) {
            p1 += __shfl_down(p1, 32); p2 += __shfl_down(p2, 32);
            p1 += __shfl_down(p1, 16); p2 += __shfl_down(p2, 16);
            if (l < 16) { atomicAdd(&stats[col], p1); atomicAdd(&stats[64 + col], p2); }
        }
    };

    if constexpr (MODE == 0) {
        if (w >= 4) {
            #pragma unroll
            for (int m = 0; m < 4; ++m) part[((w & 3) << 8) + (l << 2) + m] = acc[m];
        }
        __syncthreads();
        if (w < 4) {
            #pragma unroll
            for (int m = 0; m < 4; ++m) acc[m] += part[((w & 3) << 8) + (l << 2) + m];
            emit(acc, o0, 64, ((w & 3) << 4) + (l & 15), 64, 0.f, s0);
        }
    } else if constexpr (MODE == 1) {
        if (w < 4) emit(acc, o0, 64, (w << 4) + (l & 15), 64, 0.f, s0);
        else       emit(acc, o1, 64, ((w - 4) << 4) + (l & 15), 64, 0.f, s1);
    } else if constexpr (MODE == 2) {
        if (w > 0) {
            #pragma unroll
            for (int m = 0; m < 4; ++m) part[((w - 1) << 8) + (l << 2) + m] = acc[m];
        }
        __syncthreads();
        if (w == 0) {
            for (int i = 0; i < 7; ++i) {
                #pragma unroll
                for (int m = 0; m < 4; ++m) acc[m] += part[(i << 8) + (l << 2) + m];
            }
            int col = l & 15;
            emit(acc, o0, 4, col, 4, (col < 4) ? b0[col] : 0.f, nullptr);
        }
    } else {
        if (w < 7) {
            int col = (w << 4) + (l & 15);
            emit(acc, o0, 101, col, 101, (col < 101) ? b0[col] : 0.f, nullptr);
        } else {
            int col = l & 15;
            emit(acc, o1, 1, col, 1, b1[0], nullptr);
        }
    }
}

// ---------------- host launch ----------------
extern "C" void kernel_launch(void* const* d_in, const int* in_sizes, int n_in,
                              void* d_out, int out_size, void* d_ws, size_t ws_size,
                              hipStream_t stream) {
    const float* x    = (const float*)d_in[0];
    const float* ea   = (const float*)d_in[1];
    const int*   src  = (const int*)d_in[2];
    const int*   dst  = (const int*)d_in[3];
    const float* W1   = (const float*)d_in[4];
    const float* R1   = (const float*)d_in[5];
    const float* g1   = (const float*)d_in[6];
    const float* be1  = (const float*)d_in[7];
    const float* W2   = (const float*)d_in[8];
    const float* R2   = (const float*)d_in[9];
    const float* g2   = (const float*)d_in[10];
    const float* be2  = (const float*)d_in[11];
    const float* W3   = (const float*)d_in[12];
    const float* R3   = (const float*)d_in[13];
    const float* g3   = (const float*)d_in[14];
    const float* be3  = (const float*)d_in[15];
    const float* Wr   = (const float*)d_in[16];
    const float* Rr   = (const float*)d_in[17];
    const float* br   = (const float*)d_in[18];
    const float* Wc   = (const float*)d_in[19];
    const float* Rc   = (const float*)d_in[20];
    const float* bc   = (const float*)d_in[21];
    const float* Wo   = (const float*)d_in[22];
    const float* Ro   = (const float*)d_in[23];
    const float* bo   = (const float*)d_in[24];
    float* out = (float*)d_out;

    char* p = (char*)d_ws;
    auto alloc = [&](size_t bytes) { char* r = p; p += (bytes + 255) & ~(size_t)255; return r; };
    uint4*  mE   = (uint4*) alloc((size_t)NE * 16);
    int*    deg  = (int*)   alloc((size_t)NN * 4);
    int*    rp   = (int*)   alloc((size_t)(NN + 1) * 4);
    int*    cur  = (int*)   alloc((size_t)NN * 4);
    float*  invd = (float*) alloc((size_t)NN * 4);
    int*    bsum = (int*)   alloc((size_t)NBS * 4);
    int*    boff = (int*)   alloc((size_t)NBS * 4);
    ushort* T1   = (ushort*)alloc((size_t)64  * KT * 2);
    ushort* T23  = (ushort*)alloc((size_t)128 * KT * 2);
    ushort* Tr   = (ushort*)alloc((size_t)16  * KT * 2);
    ushort* TcTo = (ushort*)alloc((size_t)128 * KT * 2);
    float*  y1   = (float*) alloc((size_t)NN * CIN * 4);
    float*  y2   = (float*) alloc((size_t)NN * CIN * 4);
    float*  y3   = (float*) alloc((size_t)NN * CIN * 4);
    ushort* xb   = (ushort*)alloc((size_t)NN * CIN * 2);     // bf16 gather source (3.84 MB)
    float*  stats= (float*) alloc(3 * 128 * 4);
    ushort* A    = (ushort*)alloc((size_t)MROWS * KT * 2);   // ~99.9 MB
    float* st1 = stats, *st2 = stats + 128, *st3 = stats + 256;

    hipMemsetAsync(deg, 0, (size_t)NN * 4, stream);
    hipMemsetAsync(stats, 0, 3 * 128 * 4, stream);

    k_count  <<<1875, 256, 0, stream>>>(dst, deg);
    k_scan1  <<<NBS, 256, 0, stream>>>(deg, bsum);
    k_scan2  <<<1, 128, 0, stream>>>(bsum, boff);
    k_scan3  <<<NBS, 256, 0, stream>>>(deg, boff, rp, cur, invd);
    k_scatter<<<1875, 256, 0, stream>>>(ea, src, dst, cur, invd, mE);
    k_prepw  <<<336, 256, 0, stream>>>(W1,R1,W2,R2,W3,R3,Wr,Rr,Wc,Rc,Wo,Ro,T1,T23,Tr,TcTo);
    k_cvt    <<<1875, 1024, 0, stream>>>(x, xb);

    // conv1
    k_agg    <<<7500, 256, 0, stream>>>(rp, mE, xb, A);
    k_gemm<0><<<NBLK, 512, 0, stream>>>(A, T1, y1, nullptr, st1, nullptr, nullptr, nullptr);
    k_norm   <<<1875, 1024, 0, stream>>>(y1, st1, g1, be1, xb);
    // conv2 + conv3 (shared aggregation of BN1(y1))
    k_agg    <<<7500, 256, 0, stream>>>(rp, mE, xb, A);
    k_gemm<1><<<NBLK, 512, 0, stream>>>(A, T23, y2, y3, st2, st3, nullptr, nullptr);
    k_norm   <<<1875, 1024, 0, stream>>>(y2, st2, g2, be2, xb);
    // regr head on BN2(y2)
    k_agg    <<<7500, 256, 0, stream>>>(rp, mE, xb, A);
    k_gemm<2><<<NBLK, 512, 0, stream>>>(A, Tr, out + REG_OFF, nullptr, nullptr, nullptr, br, nullptr);
    k_norm   <<<1875, 1024, 0, stream>>>(y3, st3, g3, be3, xb);
    // cls + obj heads on BN3(y3)
    k_agg    <<<7500, 256, 0, stream>>>(rp, mE, xb, A);
    k_gemm<3><<<NBLK, 512, 0, stream>>>(A, TcTo, out, out + OBJ_OFF, nullptr, nullptr, bc, bo);
}

// Round 17
// 387.198 us; speedup vs baseline: 2.0431x; 2.0431x over previous
//
#include <hip/hip_runtime.h>
#include <hip/hip_bf16.h>

// ---------------- problem constants ----------------
#define NN 30000
#define NE 480000
#define CIN 64
#define KD 1600          // 25*64 spline-K dimension
#define KT 1664          // + 64 root-append columns
#define KMAC 13          // K macro-steps of 128
#define BM 64            // GEMM rows per block
#define NBLK 469         // ceil(30000/64)
#define MROWS (NBLK*BM)  // 30016 (A rows incl. pad)
#define NBS 118          // scan blocks: ceil(30000/256)
#define REG_OFF  (30000*101)
#define OBJ_OFF  (30000*105)

typedef short bf16x8 __attribute__((ext_vector_type(8)));
typedef float f32x4  __attribute__((ext_vector_type(4)));
typedef __attribute__((address_space(3))) unsigned lds_u32;
typedef __attribute__((address_space(1))) const unsigned glb_u32;

__device__ __forceinline__ ushort f2bf(float x) {
    union { float f; unsigned u; } v; v.f = x;
    unsigned r = v.u + 0x7FFFu + ((v.u >> 16) & 1u);   // RNE
    return (ushort)(r >> 16);
}
__device__ __forceinline__ float bf2f(ushort u) {
    union { unsigned i; float f; } v; v.i = ((unsigned)u) << 16; return v.f;
}
__device__ __forceinline__ float bflo(unsigned u) {
    union { unsigned i; float f; } v; v.i = u << 16; return v.f;
}
__device__ __forceinline__ float bfhi(unsigned u) {
    union { unsigned i; float f; } v; v.i = u & 0xFFFF0000u; return v.f;
}

#define WAITV2 asm volatile("s_waitcnt vmcnt(2)" ::: "memory")
#define WAITV0 asm volatile("s_waitcnt vmcnt(0)" ::: "memory")

// ---------------- graph preprocessing ----------------
__global__ void k_count(const int* __restrict__ dst, int* __restrict__ deg) {
    int e = blockIdx.x * 256 + threadIdx.x;
    if (e < NE) atomicAdd(&deg[dst[e]], 1);
}

// 3-stage parallel exclusive scan of deg[30000] -> rp/cur/invd
__global__ void k_scan1(const int* __restrict__ deg, int* __restrict__ bsum) {
    __shared__ int sred[4];
    int i = blockIdx.x * 256 + threadIdx.x;
    int v = (i < NN) ? deg[i] : 0;
    #pragma unroll
    for (int o = 32; o >= 1; o >>= 1) v += __shfl_down(v, o);
    int w = threadIdx.x >> 6, l = threadIdx.x & 63;
    if (l == 0) sred[w] = v;
    __syncthreads();
    if (threadIdx.x == 0) bsum[blockIdx.x] = sred[0] + sred[1] + sred[2] + sred[3];
}

__global__ void k_scan2(const int* __restrict__ bsum, int* __restrict__ boff) {
    __shared__ int s[128];
    int t = threadIdx.x;
    int v = (t < NBS) ? bsum[t] : 0;
    s[t] = v; __syncthreads();
    for (int o = 1; o < 128; o <<= 1) {
        int u = (t >= o) ? s[t - o] : 0;
        __syncthreads(); s[t] += u; __syncthreads();
    }
    if (t < NBS) boff[t] = s[t] - v;          // exclusive block offset
}

__global__ void k_scan3(const int* __restrict__ deg, const int* __restrict__ boff,
                        int* __restrict__ rp, int* __restrict__ cur, float* __restrict__ invd) {
    __shared__ int s[256];
    int t = threadIdx.x;
    int i = blockIdx.x * 256 + t;
    int v = (i < NN) ? deg[i] : 0;
    s[t] = v; __syncthreads();
    for (int o = 1; o < 256; o <<= 1) {
        int u = (t >= o) ? s[t - o] : 0;
        __syncthreads(); s[t] += u; __syncthreads();
    }
    int ex = s[t] - v + boff[blockIdx.x];
    if (i < NN) {
        rp[i] = ex; cur[i] = ex;
        invd[i] = 1.f / (float)(v > 0 ? v : 1);
    }
    if (i == NN - 1) rp[NN] = NE;
}

// spline basis per edge, scattered into dst-sorted order as ONE 16-B record:
// { k00 | (src<<8), bf16{B00,B01}, bf16{B10,B11}, 0 } with invd[dst] FOLDED into B.
__global__ void k_scatter(const float* __restrict__ ea, const int* __restrict__ src,
                          const int* __restrict__ dst, int* __restrict__ cur,
                          const float* __restrict__ invd, uint4* __restrict__ mE) {
    int e = blockIdx.x * 256 + threadIdx.x;
    if (e >= NE) return;
    float p0 = ea[e*3+0], p1 = ea[e*3+1];
    float v0 = p0*4.f, v1 = p1*4.f;
    float b0 = fminf(fmaxf(floorf(v0),0.f),4.f);
    float b1 = fminf(fmaxf(floorf(v1),0.f),4.f);
    float f0 = v0-b0, f1 = v1-b1;
    int i0 = (int)b0, i1 = (int)b1;
    int dn = dst[e];
    float s = invd[dn];
    float B00 = (1.f-f0)*(1.f-f1)*s;
    float B01 = (1.f-f0)*f1*s;
    float B10 = f0*(1.f-f1)*s;
    float B11 = f0*f1*s;
    int k00 = i0*5 + i1;
    int pos = atomicAdd(&cur[dn], 1);
    unsigned w01 = (unsigned)f2bf(B00) | ((unsigned)f2bf(B01) << 16);
    unsigned w23 = (unsigned)f2bf(B10) | ((unsigned)f2bf(B11) << 16);
    mE[pos] = make_uint4((unsigned)k00 | ((unsigned)src[e] << 8), w01, w23, 0u);
}

// pack+transpose weights to bf16 [outcol][KT]:
// T1: 64 rows. T23: 128 rows (W2 | W3). Tr: 16 rows (4 valid). TcTo: 128 rows (Wc 112 | Wo 16).
__global__ void k_prepw(const float* W1,const float* R1,const float* W2,const float* R2,
                        const float* W3,const float* R3,const float* Wr,const float* Rr,
                        const float* Wc,const float* Rc,const float* Wo,const float* Ro,
                        ushort* T1, ushort* T23, ushort* Tr, ushort* TcTo) {
    int b = blockIdx.x;
    const float* W; const float* R; ushort* T; int od; int col;
    if      (b < 64)  { W=W1; R=R1; T=T1  + (long)b*KT;       od=64;  col=b;     }
    else if (b < 128) { W=W2; R=R2; T=T23 + (long)(b-64)*KT;  od=64;  col=b-64;  }
    else if (b < 192) { W=W3; R=R3; T=T23 + (long)(b-64)*KT;  od=64;  col=b-128; }
    else if (b < 208) { W=Wr; R=Rr; T=Tr  + (long)(b-192)*KT; od=4;   col=b-192; }
    else if (b < 320) { W=Wc; R=Rc; T=TcTo+ (long)(b-208)*KT; od=101; col=b-208; }
    else              { W=Wo; R=Ro; T=TcTo+ (long)(b-208)*KT; od=1;   col=b-320; }
    for (int kc = threadIdx.x; kc < KT; kc += 256) {
        float v = 0.f;
        if (col < od) v = (kc < KD) ? W[(long)kc*od + col] : R[(long)(kc-KD)*od + col];
        T[kc] = f2bf(v);
    }
}

// ---------------- feature prep: bf16 gather source for conv1 ----------------
__global__ void k_cvt(const float* __restrict__ x, ushort* __restrict__ xb) {
    int idx = blockIdx.x * 1024 + threadIdx.x;
    if (idx < NN*CIN) xb[idx] = f2bf(x[idx]);
}

// ---------------- aggregation: one wave per node, r14-validated structure ----------------
// NORM: per-lane BN params from stats; applied at consume (the gathered yb is pre-norm bf16).
#define AGGC(K, A_, B_, C_, D_) case K: A_ += b0v*xu; B_ += b1v*xu; C_ += b2v*xu; D_ += b3v*xu; break;

template<bool NORM>
__global__ void k_agg(
                      const int* __restrict__ rp, const uint4* __restrict__ mE,
                      const ushort* __restrict__ f,
                      const float* __restrict__ st, const float* __restrict__ g,
                      const float* __restrict__ be, ushort* __restrict__ A) {
    int wid = (blockIdx.x * 256 + threadIdx.x) >> 6;
    wid = __builtin_amdgcn_readfirstlane(wid);   // wave-uniform -> scalar loads for rp/mE
    int l = threadIdx.x & 63;
    if (wid >= NN) return;
    float na = 0.f, nc = 0.f;
    if (NORM) {
        const float inv_n = 1.f / (float)NN;
        float mm = st[l] * inv_n;
        float var = st[64 + l] * inv_n - mm * mm;
        float rs = rsqrtf(var + 1e-5f);
        na = g[l] * rs; nc = be[l] - mm * na;
    }
    float a00=0.f,a01=0.f,a02=0.f,a03=0.f,a04=0.f;
    float a05=0.f,a06=0.f,a07=0.f,a08=0.f,a09=0.f;
    float a10=0.f,a11=0.f,a12=0.f,a13=0.f,a14=0.f;
    float a15=0.f,a16=0.f,a17=0.f,a18=0.f,a19=0.f;
    float a20=0.f,a21=0.f,a22=0.f,a23=0.f,a24=0.f;
    int beg = rp[wid], end = rp[wid + 1];
    for (int e0 = beg; e0 < end; e0 += 8) {
        // phase 1: packed edge records (uniform address -> SGPR path), one 16B load each
        uint4 m[8];
        #pragma unroll
        for (int u = 0; u < 8; ++u) {
            int e = e0 + u;
            m[u] = mE[(e < end) ? e : beg];
            if (e >= end) { m[u].y = 0u; m[u].z = 0u; }   // zero basis for tail
        }
        // phase 2: issue ALL 8 gathers (bf16, 128B/wave, L2-resident source)
        ushort xv[8];
        #pragma unroll
        for (int u = 0; u < 8; ++u) xv[u] = f[(long)(m[u].x >> 8) * CIN + l];
        __builtin_amdgcn_sched_barrier(0);
        // phase 3: consume (apply BN+ReLU to gathered value if NORM)
        #pragma unroll
        for (int u = 0; u < 8; ++u) {
            float xu = bf2f(xv[u]);
            if (NORM) xu = fmaxf(xu * na + nc, 0.f);
            float b0v = bflo(m[u].y), b1v = bfhi(m[u].y);
            float b2v = bflo(m[u].z), b3v = bfhi(m[u].z);
            int k00 = __builtin_amdgcn_readfirstlane(m[u].x & 0xFFu);
            switch (k00) {
                AGGC(0,  a00,a01,a05,a06)
                AGGC(1,  a01,a02,a06,a07)
                AGGC(2,  a02,a03,a07,a08)
                AGGC(3,  a03,a04,a08,a09)
                AGGC(5,  a05,a06,a10,a11)
                AGGC(6,  a06,a07,a11,a12)
                AGGC(7,  a07,a08,a12,a13)
                AGGC(8,  a08,a09,a13,a14)
                AGGC(10, a10,a11,a15,a16)
                AGGC(11, a11,a12,a16,a17)
                AGGC(12, a12,a13,a17,a18)
                AGGC(13, a13,a14,a18,a19)
                AGGC(15, a15,a16,a20,a21)
                AGGC(16, a16,a17,a21,a22)
                AGGC(17, a17,a18,a22,a23)
                AGGC(18, a18,a19,a23,a24)
                default: break;
            }
        }
    }
    ushort* rb = A + (long)wid * KT + l;
    #define STO(K, V) rb[K*CIN] = f2bf(V);
    STO(0,a00)  STO(1,a01)  STO(2,a02)  STO(3,a03)  STO(4,a04)
    STO(5,a05)  STO(6,a06)  STO(7,a07)  STO(8,a08)  STO(9,a09)
    STO(10,a10) STO(11,a11) STO(12,a12) STO(13,a13) STO(14,a14)
    STO(15,a15) STO(16,a16) STO(17,a17) STO(18,a18) STO(19,a19)
    STO(20,a20) STO(21,a21) STO(22,a22) STO(23,a23) STO(24,a24)
    #undef STO
    // root-append: normalized self feature
    {
        float rv = bf2f(f[(long)wid * CIN + l]);
        if (NORM) rv = fmaxf(rv * na + nc, 0.f);
        rb[KD] = f2bf(rv);
    }
}

// ---------------- GEMM: A[30016 x 1664] bf16 x B[N x 1664] bf16 -> out ----------------
// r14-validated core: BM=64, BK=128, 512 threads, triple-buffered LDS, depth-2 prefetch,
// counted vmcnt + raw s_barrier, B-loads issued before stage intrinsics.
// MODE 0: N=64  (T1)  -> yb1 (bf16) + st1, K-split [0,7)/[7,13)
// MODE 1: N=128 (T23) -> waves 0-3: yb2+st2, waves 4-7: yb3+st3 (bf16)
// MODE 2: N=16  (Tr)  -> f32 out stride 4, K round-robin + LDS reduce, bias
// MODE 3: N=128 (TcTo)-> waves 0-6: cls f32 (101, bias), wave 7: obj f32 (1 col, bias)
template<int MODE>
__global__ void k_gemm(const ushort* __restrict__ A, const ushort* __restrict__ B,
                       void* __restrict__ o0v, void* __restrict__ o1v,
                       float* __restrict__ s0, float* __restrict__ s1,
                       const float* __restrict__ b0, const float* __restrict__ b1) {
    __shared__ ushort As[3 * 8192];           // 3 x 16 KB
    f32x4* part = (f32x4*)As;                 // epilogue overlay (all loads drained by then)
    const int tid = threadIdx.x, w = tid >> 6, l = tid & 63;
    const int m0 = blockIdx.x * BM;

    int colrow;
    if constexpr (MODE == 0)      colrow = ((w & 3) << 4) + (l & 15);
    else if constexpr (MODE == 2) colrow = (l & 15);
    else                          colrow = (w << 4) + (l & 15);
    const ushort* Bp = B + (long)colrow * KT + ((l >> 4) << 3);

    // staging: wave w covers rows w*8 .. w*8+7
    const int row0 = (w << 3) + (l >> 4);
    const int row1 = row0 + 4;
    const ushort* g0 = A + (long)(m0 + row0) * KT + (((l & 15) ^ (row0 & 7)) << 3);
    const ushort* g1 = A + (long)(m0 + row1) * KT + (((l & 15) ^ (row1 & 7)) << 3);
    ushort* d0 = (ushort*)As + (w << 10);     // wave base (bytes: w*2048)
    ushort* d1 = d0 + 512;                    // + 1024 B

    auto stage = [&](int ks, int bf) {
        const ushort* sA = g0 + ks * 128;
        const ushort* sB = g1 + ks * 128;
        __builtin_amdgcn_global_load_lds((glb_u32*)sA, (lds_u32*)(d0 + bf * 8192), 16, 0, 0);
        __builtin_amdgcn_global_load_lds((glb_u32*)sB, (lds_u32*)(d1 + bf * 8192), 16, 0, 0);
    };

    f32x4 acc[4];
    #pragma unroll
    for (int m = 0; m < 4; ++m) acc[m] = (f32x4){0.f,0.f,0.f,0.f};

    stage(0, 0);
    stage(1, 1);
    WAITV2;                                   // tile 0 done, tile 1 in flight
    __builtin_amdgcn_s_barrier();
    __builtin_amdgcn_sched_barrier(0);

    for (int ks = 0; ks < KMAC; ++ks) {
        const int bufc = ks % 3;
        bool act;
        if constexpr (MODE == 0)      act = (w < 4) ? (ks < 7) : (ks >= 7);
        else if constexpr (MODE == 2) act = ((ks & 7) == w);
        else                          act = true;
        if (act) {
            bf16x8 bb[4];
            #pragma unroll
            for (int s = 0; s < 4; ++s) bb[s] = *(const bf16x8*)(Bp + ks * 128 + s * 32);
            if (ks + 2 < KMAC) stage(ks + 2, (ks + 2) % 3);   // issued AFTER B-loads
            const char* Ab = (const char*)As + bufc * 16384;
            #pragma unroll
            for (int s = 0; s < 4; ++s) {
                #pragma unroll
                for (int m = 0; m < 4; ++m) {
                    int r = (m << 4) + (l & 15);
                    int j = (s << 2) + (l >> 4);
                    bf16x8 a = *(const bf16x8*)(Ab + r * 256 + ((j ^ (r & 7)) << 4));
                    acc[m] = __builtin_amdgcn_mfma_f32_16x16x32_bf16(a, bb[s], acc[m], 0, 0, 0);
                }
            }
        } else {
            if (ks + 2 < KMAC) stage(ks + 2, (ks + 2) % 3);
        }
        if (ks < KMAC - 2) { WAITV2; } else { WAITV0; }
        __builtin_amdgcn_s_barrier();
        __builtin_amdgcn_sched_barrier(0);
    }

    // ---- epilogue (part[] overlays As; all loads drained) ----
    // f32 emit (heads)
    auto emitf = [&](f32x4* ac, float* out, int ostride, int col, int odcap, float bv) {
        #pragma unroll
        for (int m = 0; m < 4; ++m) {
            #pragma unroll
            for (int r = 0; r < 4; ++r) {
                int row = m0 + (m << 4) + ((l >> 4) << 2) + r;
                if (row < NN && col < odcap)
                    out[(long)row * ostride + col] = ac[m][r] + bv;
            }
        }
    };
    // bf16 emit + stats from f32 accumulators (hidden-layer y)
    auto emitb = [&](f32x4* ac, ushort* out, int col, float* stats) {
        float p1 = 0.f, p2 = 0.f;
        #pragma unroll
        for (int m = 0; m < 4; ++m) {
            #pragma unroll
            for (int r = 0; r < 4; ++r) {
                int row = m0 + (m << 4) + ((l >> 4) << 2) + r;
                if (row < NN) {
                    float v = ac[m][r];
                    out[(long)row * 64 + col] = f2bf(v);
                    p1 += v; p2 += v * v;
                }
            }
        }
        p1 += __shfl_down(p1, 32); p2 += __shfl_down(p2, 32);
        p1 += __shfl_down(p1, 16); p2 += __shfl_down(p2, 16);
        if (l < 16) { atomicAdd(&stats[col], p1); atomicAdd(&stats[64 + col], p2); }
    };

    if constexpr (MODE == 0) {
        if (w >= 4) {
            #pragma unroll
            for (int m = 0; m < 4; ++m) part[((w & 3) << 8) + (l << 2) + m] = acc[m];
        }
        __syncthreads();
        if (w < 4) {
            #pragma unroll
            for (int m = 0; m < 4; ++m) acc[m] += part[((w & 3) << 8) + (l << 2) + m];
            emitb(acc, (ushort*)o0v, ((w & 3) << 4) + (l & 15), s0);
        }
    } else if constexpr (MODE == 1) {
        if (w < 4) emitb(acc, (ushort*)o0v, (w << 4) + (l & 15), s0);
        else       emitb(acc, (ushort*)o1v, ((w - 4) << 4) + (l & 15), s1);
    } else if constexpr (MODE == 2) {
        if (w > 0) {
            #pragma unroll
            for (int m = 0; m < 4; ++m) part[((w - 1) << 8) + (l << 2) + m] = acc[m];
        }
        __syncthreads();
        if (w == 0) {
            for (int i = 0; i < 7; ++i) {
                #pragma unroll
                for (int m = 0; m < 4; ++m) acc[m] += part[(i << 8) + (l << 2) + m];
            }
            int col = l & 15;
            emitf(acc, (float*)o0v, 4, col, 4, (col < 4) ? b0[col] : 0.f);
        }
    } else {
        if (w < 7) {
            int col = (w << 4) + (l & 15);
            emitf(acc, (float*)o0v, 101, col, 101, (col < 101) ? b0[col] : 0.f);
        } else {
            int col = l & 15;
            emitf(acc, (float*)o1v, 1, col, 1, b1[0]);
        }
    }
}

// ---------------- host launch ----------------
extern "C" void kernel_launch(void* const* d_in, const int* in_sizes, int n_in,
                              void* d_out, int out_size, void* d_ws, size_t ws_size,
                              hipStream_t stream) {
    const float* x    = (const float*)d_in[0];
    const float* ea   = (const float*)d_in[1];
    const int*   src  = (const int*)d_in[2];
    const int*   dst  = (const int*)d_in[3];
    const float* W1   = (const float*)d_in[4];
    const float* R1   = (const float*)d_in[5];
    const float* g1   = (const float*)d_in[6];
    const float* be1  = (const float*)d_in[7];
    const float* W2   = (const float*)d_in[8];
    const float* R2   = (const float*)d_in[9];
    const float* g2   = (const float*)d_in[10];
    const float* be2  = (const float*)d_in[11];
    const float* W3   = (const float*)d_in[12];
    const float* R3   = (const float*)d_in[13];
    const float* g3   = (const float*)d_in[14];
    const float* be3  = (const float*)d_in[15];
    const float* Wr   = (const float*)d_in[16];
    const float* Rr   = (const float*)d_in[17];
    const float* br   = (const float*)d_in[18];
    const float* Wc   = (const float*)d_in[19];
    const float* Rc   = (const float*)d_in[20];
    const float* bc   = (const float*)d_in[21];
    const float* Wo   = (const float*)d_in[22];
    const float* Ro   = (const float*)d_in[23];
    const float* bo   = (const float*)d_in[24];
    float* out = (float*)d_out;

    char* p = (char*)d_ws;
    auto alloc = [&](size_t bytes) { char* r = p; p += (bytes + 255) & ~(size_t)255; return r; };
    uint4*  mE   = (uint4*) alloc((size_t)NE * 16);
    int*    deg  = (int*)   alloc((size_t)NN * 4);
    int*    rp   = (int*)   alloc((size_t)(NN + 1) * 4);
    int*    cur  = (int*)   alloc((size_t)NN * 4);
    float*  invd = (float*) alloc((size_t)NN * 4);
    int*    bsum = (int*)   alloc((size_t)NBS * 4);
    int*    boff = (int*)   alloc((size_t)NBS * 4);
    ushort* T1   = (ushort*)alloc((size_t)64  * KT * 2);
    ushort* T23  = (ushort*)alloc((size_t)128 * KT * 2);
    ushort* Tr   = (ushort*)alloc((size_t)16  * KT * 2);
    ushort* TcTo = (ushort*)alloc((size_t)128 * KT * 2);
    ushort* xb   = (ushort*)alloc((size_t)NN * CIN * 2);     // conv1 gather source (3.84 MB)
    ushort* yb1  = (ushort*)alloc((size_t)NN * CIN * 2);     // hidden bf16 y (3.84 MB each)
    ushort* yb2  = (ushort*)alloc((size_t)NN * CIN * 2);
    ushort* yb3  = (ushort*)alloc((size_t)NN * CIN * 2);
    float*  stats= (float*) alloc(3 * 128 * 4);
    ushort* A    = (ushort*)alloc((size_t)MROWS * KT * 2);   // ~99.9 MB
    float* st1 = stats, *st2 = stats + 128, *st3 = stats + 256;

    hipMemsetAsync(deg, 0, (size_t)NN * 4, stream);
    hipMemsetAsync(stats, 0, 3 * 128 * 4, stream);

    k_count  <<<1875, 256, 0, stream>>>(dst, deg);
    k_scan1  <<<NBS, 256, 0, stream>>>(deg, bsum);
    k_scan2  <<<1, 128, 0, stream>>>(bsum, boff);
    k_scan3  <<<NBS, 256, 0, stream>>>(deg, boff, rp, cur, invd);
    k_scatter<<<1875, 256, 0, stream>>>(ea, src, dst, cur, invd, mE);
    k_prepw  <<<336, 256, 0, stream>>>(W1,R1,W2,R2,W3,R3,Wr,Rr,Wc,Rc,Wo,Ro,T1,T23,Tr,TcTo);
    k_cvt    <<<1875, 1024, 0, stream>>>(x, xb);

    // conv1: agg(x) -> GEMM -> yb1 (bf16, pre-norm) + st1
    k_agg<false><<<7500, 256, 0, stream>>>(rp, mE, xb, nullptr, nullptr, nullptr, A);
    k_gemm<0><<<NBLK, 512, 0, stream>>>(A, T1, yb1, nullptr, st1, nullptr, nullptr, nullptr);
    // conv2 + conv3: agg(BN1(yb1)) shared -> GEMM -> yb2, yb3 + st2, st3
    k_agg<true><<<7500, 256, 0, stream>>>(rp, mE, yb1, st1, g1, be1, A);
    k_gemm<1><<<NBLK, 512, 0, stream>>>(A, T23, yb2, yb3, st2, st3, nullptr, nullptr);
    // regr head: agg(BN2(yb2)) -> GEMM -> out
    k_agg<true><<<7500, 256, 0, stream>>>(rp, mE, yb2, st2, g2, be2, A);
    k_gemm<2><<<NBLK, 512, 0, stream>>>(A, Tr, out + REG_OFF, nullptr, nullptr, nullptr, br, nullptr);
    // cls + obj heads: agg(BN3(yb3)) -> GEMM -> out
    k_agg<true><<<7500, 256, 0, stream>>>(rp, mE, yb3, st3, g3, be3, A);
    k_gemm<3><<<NBLK, 512, 0, stream>>>(A, TcTo, out, out + OBJ_OFF, nullptr, nullptr, bc, bo);
}